// Round 1
// baseline (10078.928 us; speedup 1.0000x reference)
//
#include <hip/hip_runtime.h>

// Zonotope abstract interpretation network.
// Physical layout: X has R=786 rows. Row 0 = center, rows 1..784 = generators,
// row 785 = the "true" (concrete) forward pass. Conv/linear add bias to rows 0
// and 785; zonotope ReLU scales rows 0..784 (with +mu on row 0) and applies a
// plain ReLU to row 785.

#define RROWS 786

// ---------------- conv 3x3 VALID, one thread per output element ----------------
__global__ void conv3x3_kernel(const float* __restrict__ in, const float* __restrict__ Wt,
                               const float* __restrict__ bias, float* __restrict__ out,
                               int C, int H, int Wd, int O, int firstLayer)
{
    const int R = RROWS;
    int OH = H - 2, OW = Wd - 2;
    long total = (long)R * O * OH * OW;
    long idx = (long)blockIdx.x * blockDim.x + threadIdx.x;
    if (idx >= total) return;
    int ow = (int)(idx % OW);
    int oh = (int)((idx / OW) % OH);
    int o  = (int)((idx / ((long)OW * OH)) % O);
    int r  = (int)(idx / ((long)OW * OH * O));
    // first layer reads the 785-row input; its "true" row is input row 0
    int rin = (firstLayer && r == R - 1) ? 0 : r;
    const float* ip = in + (long)rin * C * H * Wd;
    const float* wp = Wt + (long)o * C * 9;
    float acc = 0.f;
    for (int c = 0; c < C; ++c) {
        const float* ipc = ip + (long)c * H * Wd + (long)oh * Wd + ow;
        const float* wpc = wp + c * 9;
#pragma unroll
        for (int ky = 0; ky < 3; ++ky)
#pragma unroll
            for (int kx = 0; kx < 3; ++kx)
                acc += ipc[ky * Wd + kx] * wpc[ky * 3 + kx];
    }
    if (r == 0 || r == R - 1) acc += bias[o];
    out[idx] = acc;
}

// ---------------- GEMM (small-N fallback): C[m,n] = sum_k A[m,k]*W[n,k] ------
// 64x64 tile, BK=16, 256 threads, each computes 4x4. (verified baseline)
__global__ __launch_bounds__(256) void gemm_bt_kernel(
    const float* __restrict__ A, const float* __restrict__ W,
    const float* __restrict__ bias, float* __restrict__ C,
    int M, int N, int K)
{
    __shared__ float As[16][65];
    __shared__ float Bs[16][65];
    int tid = threadIdx.x;
    int n0 = blockIdx.x * 64;
    int m0 = blockIdx.y * 64;
    int tx = tid & 15, ty = tid >> 4;
    float acc[4][4] = {};
    for (int k0 = 0; k0 < K; k0 += 16) {
#pragma unroll
        for (int i = 0; i < 4; ++i) {
            int l = tid + i * 256;        // 0..1023
            int kk = l & 15, mm = l >> 4;
            int m = m0 + mm;
            As[kk][mm] = (m < M) ? A[(long)m * K + k0 + kk] : 0.f;
            int n = n0 + mm;
            Bs[kk][mm] = (n < N) ? W[(long)n * K + k0 + kk] : 0.f;
        }
        __syncthreads();
#pragma unroll
        for (int kk = 0; kk < 16; ++kk) {
            float a[4], b[4];
#pragma unroll
            for (int i = 0; i < 4; ++i) a[i] = As[kk][ty * 4 + i];
#pragma unroll
            for (int j = 0; j < 4; ++j) b[j] = Bs[kk][tx * 4 + j];
#pragma unroll
            for (int i = 0; i < 4; ++i)
#pragma unroll
                for (int j = 0; j < 4; ++j)
                    acc[i][j] += a[i] * b[j];
        }
        __syncthreads();
    }
#pragma unroll
    for (int i = 0; i < 4; ++i) {
        int m = m0 + ty * 4 + i;
        if (m >= M) continue;
#pragma unroll
        for (int j = 0; j < 4; ++j) {
            int n = n0 + tx * 4 + j;
            if (n >= N) continue;
            float v = acc[i][j];
            if (m == 0 || m == M - 1) v += bias[n];
            C[(long)m * N + n] = v;
        }
    }
}

// ---------------- GEMM (main): 128x128 tile, BK=16, 256 threads, 8x8/thread --
// C[m,n] = sum_k A[m,k] * W[n,k]  (+bias on rows 0 and M-1)
// LDS tiles stored transposed As[k][m], Bs[k][n]; fragments read as float4
// (ds_read_b128): 4 LDS vector reads feed 64 FMAs per kk per thread.
// Requires K % 16 == 0 (true for all FC layers: 12800/6272/512/256).
__global__ __launch_bounds__(256) void gemm128_kernel(
    const float* __restrict__ A, const float* __restrict__ W,
    const float* __restrict__ bias, float* __restrict__ C,
    int M, int N, int K)
{
    __shared__ float As[16][128];
    __shared__ float Bs[16][128];
    const int tid = threadIdx.x;
    const int n0 = blockIdx.x * 128;
    const int m0 = blockIdx.y * 128;
    const int tx = tid & 15;   // n-dim (x4)
    const int ty = tid >> 4;   // m-dim (x4)
    float acc[2][2][4][4] = {}; // [mh][nh][i][j]

    for (int k0 = 0; k0 < K; k0 += 16) {
        // stage 128x16 A-tile and B-tile, transposed into LDS.
        // 512 float4 loads per tile -> 2 per thread, coalesced along k.
#pragma unroll
        for (int i = 0; i < 2; ++i) {
            int l  = tid + i * 256;     // 0..511
            int mm = l >> 2;            // 0..127 (row within tile)
            int kq = (l & 3) * 4;       // 0,4,8,12 (k-quad)
            int m = m0 + mm;
            float4 av = (m < M) ? *(const float4*)(A + (long)m * K + k0 + kq)
                                : make_float4(0.f, 0.f, 0.f, 0.f);
            As[kq + 0][mm] = av.x; As[kq + 1][mm] = av.y;
            As[kq + 2][mm] = av.z; As[kq + 3][mm] = av.w;
            int n = n0 + mm;
            float4 bv = (n < N) ? *(const float4*)(W + (long)n * K + k0 + kq)
                                : make_float4(0.f, 0.f, 0.f, 0.f);
            Bs[kq + 0][mm] = bv.x; Bs[kq + 1][mm] = bv.y;
            Bs[kq + 2][mm] = bv.z; Bs[kq + 3][mm] = bv.w;
        }
        __syncthreads();
#pragma unroll
        for (int kk = 0; kk < 16; ++kk) {
            float4 a0 = *(const float4*)&As[kk][ty * 4];
            float4 a1 = *(const float4*)&As[kk][64 + ty * 4];
            float4 b0 = *(const float4*)&Bs[kk][tx * 4];
            float4 b1 = *(const float4*)&Bs[kk][64 + tx * 4];
            float a[2][4] = { { a0.x, a0.y, a0.z, a0.w },
                              { a1.x, a1.y, a1.z, a1.w } };
            float b[2][4] = { { b0.x, b0.y, b0.z, b0.w },
                              { b1.x, b1.y, b1.z, b1.w } };
#pragma unroll
            for (int mh = 0; mh < 2; ++mh)
#pragma unroll
                for (int i = 0; i < 4; ++i)
#pragma unroll
                    for (int nh = 0; nh < 2; ++nh)
#pragma unroll
                        for (int j = 0; j < 4; ++j)
                            acc[mh][nh][i][j] += a[mh][i] * b[nh][j];
        }
        __syncthreads();
    }

    // epilogue: bias on rows 0 and M-1, guarded scalar stores
#pragma unroll
    for (int mh = 0; mh < 2; ++mh) {
#pragma unroll
        for (int i = 0; i < 4; ++i) {
            int m = m0 + mh * 64 + ty * 4 + i;
            if (m >= M) continue;
            bool biasRow = (m == 0) || (m == M - 1);
#pragma unroll
            for (int nh = 0; nh < 2; ++nh) {
#pragma unroll
                for (int j = 0; j < 4; ++j) {
                    int n = n0 + nh * 64 + tx * 4 + j;
                    if (n >= N) continue;
                    float v = acc[mh][nh][i][j];
                    if (biasRow) v += bias[n];
                    C[(long)m * N + n] = v;
                }
            }
        }
    }
}

// ---------------- per-neuron bounds + ReLU coefficients ----------------
__global__ void bounds_kernel(const float* __restrict__ y, int N,
                              float* __restrict__ coef, float* __restrict__ mu,
                              float* __restrict__ omin, float* __restrict__ omax)
{
    const int R = RROWS;
    int n = blockIdx.x * blockDim.x + threadIdx.x;
    if (n >= N) return;
    float eps = 0.f;
    for (int r = 1; r < R - 1; ++r)
        eps += fabsf(y[(long)r * N + n]);
    float y0 = y[n];
    float mn = y0 - eps, mx = y0 + eps;
    float span = mx - mn;
    float lam = mx / (span > 0.f ? span : 1.0f);
    bool crossing = (mn < 0.f) && (mx > 0.f);
    float c = (mx <= 0.f) ? 0.f : ((mn >= 0.f) ? 1.f : lam);
    float m_ = crossing ? (-lam * mn * 0.5f) : 0.f;
    coef[n] = c;
    mu[n] = m_;
    float nx0 = c * y0 + m_;
    float ne = c * eps + m_;
    omin[n] = nx0 - ne;
    omax[n] = nx0 + ne;
}

__global__ void apply_relu_kernel(float* __restrict__ y, int N,
                                  const float* __restrict__ coef,
                                  const float* __restrict__ mu)
{
    const int R = RROWS;
    long total = (long)R * N;
    long idx = (long)blockIdx.x * blockDim.x + threadIdx.x;
    if (idx >= total) return;
    int n = (int)(idx % N);
    int r = (int)(idx / N);
    float v = y[idx];
    if (r == R - 1) {
        v = fmaxf(v, 0.f);      // true row: plain ReLU
    } else {
        v *= coef[n];
        if (r == 0) v += mu[n]; // center row gets +mu
    }
    y[idx] = v;
}

// ---------------- final output assembly ----------------
// out = concat( x[0:785, 0:8] , x_min[8], x_max[8], x_true[8] ) = 6304 floats
__global__ void write_out_kernel(const float* __restrict__ y,
                                 const float* __restrict__ omin,
                                 const float* __restrict__ omax,
                                 float* __restrict__ out)
{
    int i = blockIdx.x * blockDim.x + threadIdx.x;
    if (i < 6280) out[i] = y[i];
    else if (i < 6288) out[i] = omin[i - 6280];
    else if (i < 6296) out[i] = omax[i - 6288];
    else if (i < 6304) out[i] = y[785 * 8 + (i - 6296)];
}

extern "C" void kernel_launch(void* const* d_in, const int* in_sizes, int n_in,
                              void* d_out, int out_size, void* d_ws, size_t ws_size,
                              hipStream_t stream)
{
    const float* x   = (const float*)d_in[0];
    const float* cW1 = (const float*)d_in[1];  const float* cb1 = (const float*)d_in[2];
    const float* cW2 = (const float*)d_in[3];  const float* cb2 = (const float*)d_in[4];
    const float* cW3 = (const float*)d_in[5];  const float* cb3 = (const float*)d_in[6];
    const float* cW4 = (const float*)d_in[7];  const float* cb4 = (const float*)d_in[8];
    const float* fW[7] = { (const float*)d_in[9],  (const float*)d_in[11],
                           (const float*)d_in[13], (const float*)d_in[15],
                           (const float*)d_in[17], (const float*)d_in[19],
                           (const float*)d_in[21] };
    const float* fb[7] = { (const float*)d_in[10], (const float*)d_in[12],
                           (const float*)d_in[14], (const float*)d_in[16],
                           (const float*)d_in[18], (const float*)d_in[20],
                           (const float*)d_in[22] };
    const int fcK[7] = { 12800, 6272, 6272, 6272, 6272, 512, 256 };
    const int fcN[7] = { 6272, 6272, 6272, 6272, 512, 256, 8 };

    const int R = RROWS;
    const size_t bufElems = (size_t)R * 15488; // largest intermediate (after conv3)
    float* buf0 = (float*)d_ws;
    float* buf1 = buf0 + bufElems;
    float* coef = buf1 + bufElems;
    float* mu   = coef + 15488;
    float* omin = mu + 15488;
    float* omax = omin + 15488;

    auto relu_stage = [&](float* y, int N) {
        bounds_kernel<<<(N + 255) / 256, 256, 0, stream>>>(y, N, coef, mu, omin, omax);
        long total = (long)R * N;
        apply_relu_kernel<<<(int)((total + 255) / 256), 256, 0, stream>>>(y, N, coef, mu);
    };
    auto conv_stage = [&](const float* in, const float* Wt, const float* b,
                          float* out, int C, int H, int O, int first) {
        long total = (long)R * O * (H - 2) * (H - 2);
        conv3x3_kernel<<<(int)((total + 255) / 256), 256, 0, stream>>>(
            in, Wt, b, out, C, H, H, O, first);
        relu_stage(out, O * (H - 2) * (H - 2));
    };
    auto fc_stage = [&](const float* in, int li, float* out) {
        int N = fcN[li], K = fcK[li];
        if (N >= 128) {
            dim3 grid((N + 127) / 128, (R + 127) / 128);
            gemm128_kernel<<<grid, 256, 0, stream>>>(in, fW[li], fb[li], out, R, N, K);
        } else {
            dim3 grid((N + 63) / 64, (R + 63) / 64);
            gemm_bt_kernel<<<grid, 256, 0, stream>>>(in, fW[li], fb[li], out, R, N, K);
        }
        relu_stage(out, N);
    };

    conv_stage(x,    cW1, cb1, buf0,  1, 28, 16, 1); // -> [786,16,26,26]
    conv_stage(buf0, cW2, cb2, buf1, 16, 26, 16, 0); // -> [786,16,24,24]
    conv_stage(buf1, cW3, cb3, buf0, 16, 24, 32, 0); // -> [786,32,22,22]
    conv_stage(buf0, cW4, cb4, buf1, 32, 22, 32, 0); // -> [786,32,20,20] = K 12800

    fc_stage(buf1, 0, buf0);
    fc_stage(buf0, 1, buf1);
    fc_stage(buf1, 2, buf0);
    fc_stage(buf0, 3, buf1);
    fc_stage(buf1, 4, buf0);
    fc_stage(buf0, 5, buf1);
    fc_stage(buf1, 6, buf0);   // -> [786, 8]

    write_out_kernel<<<(6304 + 255) / 256, 256, 0, stream>>>(buf0, omin, omax, (float*)d_out);
}